// Round 1
// baseline (825.315 us; speedup 1.0000x reference)
//
#include <hip/hip_runtime.h>
#include <math.h>

#define N_WIRES 8
#define N_LAYERS 6

// ---------------------------------------------------------------------------
// Precompute, per (layer, wire): U = RZ(w2)*RY(w1)*RX(w0) and V such that the
// fused gate (weight-gates ∘ encoding-gate) is G = c*U + s*V, where
// (c,s) = (cos(x0/2), sin(x0/2)) for even wires (RX encoding) and
// (cos(x1/2), sin(x1/2)) for odd wires (RY encoding).
//   even: V = U * (-iX)  -> V[r][0] = -i*U[r][1], V[r][1] = -i*U[r][0]
//   odd : V = U * [[0,-1],[1,0]] -> V[r][0] = U[r][1], V[r][1] = -U[r][0]
// Layout in ws: 48 * 16 floats: [U00r,U00i,U01r,U01i,U10r,U10i,U11r,U11i,
//                                V00r,V00i,V01r,V01i,V10r,V10i,V11r,V11i]
// ---------------------------------------------------------------------------
__global__ void precompute_uv(const float* __restrict__ w, float* __restrict__ uv) {
    int t = threadIdx.x;
    if (t >= N_LAYERS * N_WIRES) return;
    int i = t & 7;
    float wx = w[t * 3 + 0], wy = w[t * 3 + 1], wz = w[t * 3 + 2];
    float sx, cx, sy, cy, sz, cz;
    sincosf(0.5f * wx, &sx, &cx);
    sincosf(0.5f * wy, &sy, &cy);
    sincosf(0.5f * wz, &sz, &cz);
    // A = RY*RX
    float A00r = cy * cx, A00i = sy * sx;
    float A01r = -sy * cx, A01i = -cy * sx;
    float A10r = sy * cx, A10i = -cy * sx;
    float A11r = cy * cx, A11i = -sy * sx;
    // U = RZ*A : row0 *= (cz - i sz), row1 *= (cz + i sz)
    float U00r = A00r * cz + A00i * sz, U00i = A00i * cz - A00r * sz;
    float U01r = A01r * cz + A01i * sz, U01i = A01i * cz - A01r * sz;
    float U10r = A10r * cz - A10i * sz, U10i = A10i * cz + A10r * sz;
    float U11r = A11r * cz - A11i * sz, U11i = A11i * cz + A11r * sz;
    float V00r, V00i, V01r, V01i, V10r, V10i, V11r, V11i;
    if ((i & 1) == 0) {
        V00r = U01i; V00i = -U01r;
        V01r = U00i; V01i = -U00r;
        V10r = U11i; V10i = -U11r;
        V11r = U10i; V11i = -U10r;
    } else {
        V00r = U01r;  V00i = U01i;
        V01r = -U00r; V01i = -U00i;
        V10r = U11r;  V10i = U11i;
        V11r = -U10r; V11i = -U10i;
    }
    float* o = uv + t * 16;
    o[0] = U00r; o[1] = U00i; o[2] = U01r; o[3] = U01i;
    o[4] = U10r; o[5] = U10i; o[6] = U11r; o[7] = U11i;
    o[8] = V00r; o[9] = V00i; o[10] = V01r; o[11] = V01i;
    o[12] = V10r; o[13] = V10i; o[14] = V11r; o[15] = V11i;
}

// ---------------------------------------------------------------------------
// One wave (64 lanes) simulates one batch element. Amplitude index
// idx(0..255) = lane*4 + j ; wire w lives at bit p = 7 - w of idx.
// p in {0,1}: intra-lane register pair; p >= 2: cross-lane via shfl_xor.
// ---------------------------------------------------------------------------
__global__ __launch_bounds__(256) void qnn_kernel(const float* __restrict__ x,
                                                  const float* __restrict__ uv,
                                                  float* __restrict__ out, int B) {
    const int lane = threadIdx.x & 63;
    const int b = blockIdx.x * (blockDim.x >> 6) + (threadIdx.x >> 6);
    if (b >= B) return;

    float x0 = x[2 * b], x1 = x[2 * b + 1];
    float s0, c0, s1, c1;
    sincosf(0.5f * x0, &s0, &c0);
    sincosf(0.5f * x1, &s1, &c1);

    float ar[4] = {0.f, 0.f, 0.f, 0.f}, ai[4] = {0.f, 0.f, 0.f, 0.f};
    if (lane == 0) ar[0] = 1.0f;

    for (int l = 0; l < N_LAYERS; ++l) {
        const float* base = uv + l * 128;
        // 8 fused 1q gates
        #pragma unroll
        for (int i = 0; i < 8; ++i) {
            const float* g = base + i * 16;
            float ce = (i & 1) ? c1 : c0;
            float se = (i & 1) ? s1 : s0;
            float g00r = ce * g[0] + se * g[8],  g00i = ce * g[1] + se * g[9];
            float g01r = ce * g[2] + se * g[10], g01i = ce * g[3] + se * g[11];
            float g10r = ce * g[4] + se * g[12], g10i = ce * g[5] + se * g[13];
            float g11r = ce * g[6] + se * g[14], g11i = ce * g[7] + se * g[15];
            const int p = 7 - i;
            if (p >= 2) {
                const int m = 1 << (p - 2);
                const bool hi = (lane >> (p - 2)) & 1;
                float cor = hi ? g11r : g00r, coi = hi ? g11i : g00i;
                float cpr = hi ? g10r : g01r, cpi = hi ? g10i : g01i;
                #pragma unroll
                for (int j = 0; j < 4; ++j) {
                    float br = __shfl_xor(ar[j], m);
                    float bi = __shfl_xor(ai[j], m);
                    float nr = cor * ar[j] - coi * ai[j] + cpr * br - cpi * bi;
                    float ni = cor * ai[j] + coi * ar[j] + cpr * bi + cpi * br;
                    ar[j] = nr; ai[j] = ni;
                }
            } else {
                const int m = 1 << p;
                #pragma unroll
                for (int j0 = 0; j0 < 4; ++j0) {
                    if (j0 & m) continue;
                    const int j1 = j0 | m;
                    float a_r = ar[j0], a_i = ai[j0], b_r = ar[j1], b_i = ai[j1];
                    ar[j0] = g00r * a_r - g00i * a_i + g01r * b_r - g01i * b_i;
                    ai[j0] = g00r * a_i + g00i * a_r + g01r * b_i + g01i * b_r;
                    ar[j1] = g10r * a_r - g10i * a_i + g11r * b_r - g11i * b_i;
                    ai[j1] = g10r * a_i + g10i * a_r + g11r * b_i + g11i * b_r;
                }
            }
        }
        // CNOT chain (c,t) = (i,i+1): pc = 7-i, pt = 6-i
        #pragma unroll
        for (int i = 0; i < 7; ++i) {
            const int pc = 7 - i, pt = 6 - i;
            if (pt >= 2) {
                const int m = 1 << (pt - 2);
                const bool ctrl = (lane >> (pc - 2)) & 1;
                #pragma unroll
                for (int j = 0; j < 4; ++j) {
                    float br = __shfl_xor(ar[j], m);
                    float bi = __shfl_xor(ai[j], m);
                    ar[j] = ctrl ? br : ar[j];
                    ai[j] = ctrl ? bi : ai[j];
                }
            } else if (pt == 1) {  // pc==2: ctrl = lane bit0; swap regs j <-> j^2
                const bool ctrl = lane & 1;
                float n0r = ctrl ? ar[2] : ar[0], n0i = ctrl ? ai[2] : ai[0];
                float n2r = ctrl ? ar[0] : ar[2], n2i = ctrl ? ai[0] : ai[2];
                float n1r = ctrl ? ar[3] : ar[1], n1i = ctrl ? ai[3] : ai[1];
                float n3r = ctrl ? ar[1] : ar[3], n3i = ctrl ? ai[1] : ai[3];
                ar[0] = n0r; ai[0] = n0i; ar[1] = n1r; ai[1] = n1i;
                ar[2] = n2r; ai[2] = n2i; ar[3] = n3r; ai[3] = n3i;
            } else {  // pc==1, pt==0: within-lane swap j=2 <-> j=3
                float tr = ar[2], ti = ai[2];
                ar[2] = ar[3]; ai[2] = ai[3];
                ar[3] = tr;    ai[3] = ti;
            }
        }
    }

    // probabilities and <Z_i>
    float p0 = ar[0] * ar[0] + ai[0] * ai[0];
    float p1 = ar[1] * ar[1] + ai[1] * ai[1];
    float p2 = ar[2] * ar[2] + ai[2] * ai[2];
    float p3 = ar[3] * ar[3] + ai[3] * ai[3];
    float sAll = p0 + p1 + p2 + p3;

    float ev[8];
    #pragma unroll
    for (int i = 0; i < 6; ++i) {  // wire i: bit p=7-i -> lane bit (5-i)
        ev[i] = ((lane >> (5 - i)) & 1) ? -sAll : sAll;
    }
    ev[6] = p0 + p1 - p2 - p3;  // bit1 of j
    ev[7] = p0 - p1 + p2 - p3;  // bit0 of j

    #pragma unroll
    for (int i = 0; i < 8; ++i) {
        #pragma unroll
        for (int s = 1; s < 64; s <<= 1) ev[i] += __shfl_xor(ev[i], s);
    }

    if (lane == 0) {
        const float PI = 3.14159265358979323846f;
        float4* o = (float4*)(out + (size_t)b * 8);
        o[0] = make_float4(PI * ev[0], PI * ev[1], PI * ev[2], PI * ev[3]);
        o[1] = make_float4(PI * ev[4], PI * ev[5], PI * ev[6], PI * ev[7]);
    }
}

extern "C" void kernel_launch(void* const* d_in, const int* in_sizes, int n_in,
                              void* d_out, int out_size, void* d_ws, size_t ws_size,
                              hipStream_t stream) {
    (void)n_in; (void)out_size; (void)ws_size;
    const float* x = (const float*)d_in[0];
    const float* w = (const float*)d_in[1];
    float* out = (float*)d_out;
    float* uv = (float*)d_ws;  // 48*16*4 = 3072 bytes
    const int B = in_sizes[0] / 2;

    hipLaunchKernelGGL(precompute_uv, dim3(1), dim3(64), 0, stream, w, uv);

    const int wavesPerBlock = 4;  // block = 256 threads
    const int grid = (B + wavesPerBlock - 1) / wavesPerBlock;
    hipLaunchKernelGGL(qnn_kernel, dim3(grid), dim3(256), 0, stream, x, uv, out, B);
}

// Round 2
// 819.728 us; speedup vs baseline: 1.0068x; 1.0068x over previous
//
#include <hip/hip_runtime.h>
#include <math.h>

#define N_WIRES 8
#define N_LAYERS 6

// ---------------------------------------------------------------------------
// Precompute, per (layer, wire): U = RZ(w2)*RY(w1)*RX(w0) and V such that the
// fused gate (weight-gates ∘ encoding-gate) is G = c*U + s*V, where
// (c,s) = (cos(x0/2), sin(x0/2)) for even wires (RX encoding) and
// (cos(x1/2), sin(x1/2)) for odd wires (RY encoding).
//   even: V = U * (-iX)   odd: V = U * [[0,-1],[1,0]]
// Layout: 48 * 16 floats [U00r,U00i,U01r,U01i,U10r,U10i,U11r,U11i,
//                         V00r,V00i,V01r,V01i,V10r,V10i,V11r,V11i]
// ---------------------------------------------------------------------------
__global__ void precompute_uv(const float* __restrict__ w, float* __restrict__ uv) {
    int t = threadIdx.x;
    if (t >= N_LAYERS * N_WIRES) return;
    int i = t & 7;
    float wx = w[t * 3 + 0], wy = w[t * 3 + 1], wz = w[t * 3 + 2];
    float sx, cx, sy, cy, sz, cz;
    sincosf(0.5f * wx, &sx, &cx);
    sincosf(0.5f * wy, &sy, &cy);
    sincosf(0.5f * wz, &sz, &cz);
    float A00r = cy * cx, A00i = sy * sx;
    float A01r = -sy * cx, A01i = -cy * sx;
    float A10r = sy * cx, A10i = -cy * sx;
    float A11r = cy * cx, A11i = -sy * sx;
    float U00r = A00r * cz + A00i * sz, U00i = A00i * cz - A00r * sz;
    float U01r = A01r * cz + A01i * sz, U01i = A01i * cz - A01r * sz;
    float U10r = A10r * cz - A10i * sz, U10i = A10i * cz + A10r * sz;
    float U11r = A11r * cz - A11i * sz, U11i = A11i * cz + A11r * sz;
    float V00r, V00i, V01r, V01i, V10r, V10i, V11r, V11i;
    if ((i & 1) == 0) {
        V00r = U01i; V00i = -U01r;
        V01r = U00i; V01i = -U00r;
        V10r = U11i; V10i = -U11r;
        V11r = U10i; V11i = -U10r;
    } else {
        V00r = U01r;  V00i = U01i;
        V01r = -U00r; V01i = -U00i;
        V10r = U11r;  V10i = U11i;
        V11r = -U10r; V11i = -U10i;
    }
    float* o = uv + t * 16;
    o[0] = U00r; o[1] = U00i; o[2] = U01r; o[3] = U01i;
    o[4] = U10r; o[5] = U10i; o[6] = U11r; o[7] = U11i;
    o[8] = V00r; o[9] = V00i; o[10] = V01r; o[11] = V01i;
    o[12] = V10r; o[13] = V10i; o[14] = V11r; o[15] = V11i;
}

// ---------------------------------------------------------------------------
// Mapping: 16 lanes per batch element (4 elements per wave64).
// Amplitude idx(0..255): bits 7..4 = lane bits 3..0 (sub-lane), bits 3..0 = reg j.
// Wire i lives at idx bit p = 7-i:  wires 0..3 -> lane bits 3..0 (cross-lane,
// imm ds_swizzle, masks 8/4/2/1 — all inside 32-lane swizzle groups);
// wires 4..7 -> reg bits 3..0 (intra-lane register pairs).
// ---------------------------------------------------------------------------

#define SWZ_XOR(m) (((m) << 10) | 0x1F)

template <int PAT>
__device__ __forceinline__ float swz(float v) {
    return __int_as_float(__builtin_amdgcn_ds_swizzle(__float_as_int(v), PAT));
}

template <int LB>
__device__ __forceinline__ void gate_cross(float (&ar)[16], float (&ai)[16], int lane,
                                           float g00r, float g00i, float g01r, float g01i,
                                           float g10r, float g10i, float g11r, float g11i) {
    const bool hi = (lane >> LB) & 1;
    float d0r = hi ? g11r : g00r, d0i = hi ? g11i : g00i;
    float d1r = hi ? g10r : g01r, d1i = hi ? g10i : g01i;
    #pragma unroll
    for (int j = 0; j < 16; ++j) {
        float br = swz<SWZ_XOR(1 << LB)>(ar[j]);
        float bi = swz<SWZ_XOR(1 << LB)>(ai[j]);
        float nr = d0r * ar[j] - d0i * ai[j] + d1r * br - d1i * bi;
        float ni = d0r * ai[j] + d0i * ar[j] + d1r * bi + d1i * br;
        ar[j] = nr; ai[j] = ni;
    }
}

template <int RB>
__device__ __forceinline__ void gate_intra(float (&ar)[16], float (&ai)[16], int lane,
                                           float g00r, float g00i, float g01r, float g01i,
                                           float g10r, float g10i, float g11r, float g11i) {
    (void)lane;
    #pragma unroll
    for (int j0 = 0; j0 < 16; ++j0) {
        if (j0 & (1 << RB)) continue;
        const int j1 = j0 | (1 << RB);
        float a_r = ar[j0], a_i = ai[j0], b_r = ar[j1], b_i = ai[j1];
        ar[j0] = g00r * a_r - g00i * a_i + g01r * b_r - g01i * b_i;
        ai[j0] = g00r * a_i + g00i * a_r + g01r * b_i + g01i * b_r;
        ar[j1] = g10r * a_r - g10i * a_i + g11r * b_r - g11i * b_i;
        ai[j1] = g10r * a_i + g10i * a_r + g11r * b_i + g11i * b_r;
    }
}

template <int CB, int TB>
__device__ __forceinline__ void cnot_cross(float (&ar)[16], float (&ai)[16], int lane) {
    const bool ctrl = (lane >> CB) & 1;
    #pragma unroll
    for (int j = 0; j < 16; ++j) {
        float br = swz<SWZ_XOR(1 << TB)>(ar[j]);
        float bi = swz<SWZ_XOR(1 << TB)>(ai[j]);
        ar[j] = ctrl ? br : ar[j];
        ai[j] = ctrl ? bi : ai[j];
    }
}

#define APPLY(IDX, CE, SE, FN, BIT)                                              \
    {                                                                            \
        const float* g = base + (IDX) * 16;                                      \
        float q00r = (CE) * g[0] + (SE) * g[8],  q00i = (CE) * g[1] + (SE) * g[9];   \
        float q01r = (CE) * g[2] + (SE) * g[10], q01i = (CE) * g[3] + (SE) * g[11];  \
        float q10r = (CE) * g[4] + (SE) * g[12], q10i = (CE) * g[5] + (SE) * g[13];  \
        float q11r = (CE) * g[6] + (SE) * g[14], q11i = (CE) * g[7] + (SE) * g[15];  \
        FN<BIT>(ar, ai, lane, q00r, q00i, q01r, q01i, q10r, q10i, q11r, q11i);   \
    }

#define SWAPR(a, b)                                   \
    {                                                 \
        float t = ar[a]; ar[a] = ar[b]; ar[b] = t;    \
        t = ai[a]; ai[a] = ai[b]; ai[b] = t;          \
    }

__global__ __launch_bounds__(256) void qnn_kernel(const float* __restrict__ x,
                                                  const float* __restrict__ uv,
                                                  float* __restrict__ out, int B) {
    const int lane = threadIdx.x & 63;
    const int sub = lane & 15;  // lane within element group
    const int wave = blockIdx.x * (blockDim.x >> 6) + (threadIdx.x >> 6);
    const int b = wave * 4 + (lane >> 4);
    if (b >= B) return;

    float2 xv = ((const float2*)x)[b];
    float s0, c0, s1, c1;
    sincosf(0.5f * xv.x, &s0, &c0);
    sincosf(0.5f * xv.y, &s1, &c1);

    float ar[16], ai[16];
    #pragma unroll
    for (int j = 0; j < 16; ++j) { ar[j] = 0.f; ai[j] = 0.f; }
    if (sub == 0) ar[0] = 1.0f;

    for (int l = 0; l < N_LAYERS; ++l) {
        const float* base = uv + l * 128;
        // 8 fused (encode ∘ RX ∘ RY ∘ RZ) gates, wire i at idx bit 7-i
        APPLY(0, c0, s0, gate_cross, 3)
        APPLY(1, c1, s1, gate_cross, 2)
        APPLY(2, c0, s0, gate_cross, 1)
        APPLY(3, c1, s1, gate_cross, 0)
        APPLY(4, c0, s0, gate_intra, 3)
        APPLY(5, c1, s1, gate_intra, 2)
        APPLY(6, c0, s0, gate_intra, 1)
        APPLY(7, c1, s1, gate_intra, 0)
        // CNOT chain
        cnot_cross<3, 2>(ar, ai, lane);  // (0,1)
        cnot_cross<2, 1>(ar, ai, lane);  // (1,2)
        cnot_cross<1, 0>(ar, ai, lane);  // (2,3)
        {  // (3,4): ctrl lane bit 0, target reg bit 3
            const bool ctrl = lane & 1;
            float tr[16], ti[16];
            #pragma unroll
            for (int j = 0; j < 16; ++j) { tr[j] = ar[j]; ti[j] = ai[j]; }
            #pragma unroll
            for (int j = 0; j < 16; ++j) {
                ar[j] = ctrl ? tr[j ^ 8] : tr[j];
                ai[j] = ctrl ? ti[j ^ 8] : ti[j];
            }
        }
        // (4,5): ctrl reg bit 3, tgt reg bit 2 — static register permutation
        SWAPR(8, 12) SWAPR(9, 13) SWAPR(10, 14) SWAPR(11, 15)
        // (5,6): ctrl reg bit 2, tgt reg bit 1
        SWAPR(4, 6) SWAPR(5, 7) SWAPR(12, 14) SWAPR(13, 15)
        // (6,7): ctrl reg bit 1, tgt reg bit 0
        SWAPR(2, 3) SWAPR(6, 7) SWAPR(10, 11) SWAPR(14, 15)
    }

    // probabilities and <Z_i>
    float p[16];
    #pragma unroll
    for (int j = 0; j < 16; ++j) p[j] = ar[j] * ar[j] + ai[j] * ai[j];

    float tot = 0.f, e4 = 0.f, e5 = 0.f, e6 = 0.f, e7 = 0.f;
    #pragma unroll
    for (int j = 0; j < 16; ++j) {
        tot += p[j];
        e4 += (j & 8) ? -p[j] : p[j];
        e5 += (j & 4) ? -p[j] : p[j];
        e6 += (j & 2) ? -p[j] : p[j];
        e7 += (j & 1) ? -p[j] : p[j];
    }
    float ev[8];
    ev[0] = ((lane >> 3) & 1) ? -tot : tot;
    ev[1] = ((lane >> 2) & 1) ? -tot : tot;
    ev[2] = ((lane >> 1) & 1) ? -tot : tot;
    ev[3] = (lane & 1) ? -tot : tot;
    ev[4] = e4; ev[5] = e5; ev[6] = e6; ev[7] = e7;

    #pragma unroll
    for (int i = 0; i < 8; ++i) {
        ev[i] += swz<SWZ_XOR(1)>(ev[i]);
        ev[i] += swz<SWZ_XOR(2)>(ev[i]);
        ev[i] += swz<SWZ_XOR(4)>(ev[i]);
        ev[i] += swz<SWZ_XOR(8)>(ev[i]);
    }

    if (sub == 0) {
        const float PI = 3.14159265358979323846f;
        float4* o = (float4*)(out + (size_t)b * 8);
        o[0] = make_float4(PI * ev[0], PI * ev[1], PI * ev[2], PI * ev[3]);
        o[1] = make_float4(PI * ev[4], PI * ev[5], PI * ev[6], PI * ev[7]);
    }
}

extern "C" void kernel_launch(void* const* d_in, const int* in_sizes, int n_in,
                              void* d_out, int out_size, void* d_ws, size_t ws_size,
                              hipStream_t stream) {
    (void)n_in; (void)out_size; (void)ws_size;
    const float* x = (const float*)d_in[0];
    const float* w = (const float*)d_in[1];
    float* out = (float*)d_out;
    float* uv = (float*)d_ws;  // 48*16*4 = 3072 bytes
    const int B = in_sizes[0] / 2;

    hipLaunchKernelGGL(precompute_uv, dim3(1), dim3(64), 0, stream, w, uv);

    const int elemsPerBlock = 16;  // 256 threads = 4 waves * 4 elements
    const int grid = (B + elemsPerBlock - 1) / elemsPerBlock;
    hipLaunchKernelGGL(qnn_kernel, dim3(grid), dim3(256), 0, stream, x, uv, out, B);
}

// Round 3
// 186.971 us; speedup vs baseline: 4.4141x; 4.3843x over previous
//
#include <hip/hip_runtime.h>
#include <math.h>

#define N_WIRES 8
#define N_LAYERS 6
#define NG 49          // grid per axis (frequencies |n|<=24 -> 49 samples exact)
#define NG2 (NG * NG)  // 2401
#define FPAD 52        // padded row length for F (13 x float4)

// ---------------------------------------------------------------------------
// ws layout (bytes):
//   uv : [0,        3072)              48 gates x 16 floats
//   E  : [3072,     80000)             8 x 2401 floats (grid EVs, [i][a*49+b])
//   G  : [80128,    157056)            8 x 49 x 49 floats (E * T over b)
//   F  : [157056,   238592)            8 x 49 x FPAD floats (T^T * G, padded)
// ---------------------------------------------------------------------------
#define WS_E_OFF 3072
#define WS_G_OFF 80128
#define WS_F_OFF 157056

// ---------------------------------------------------------------------------
// Per (layer, wire): U = RZ(w2)*RY(w1)*RX(w0) and V with fused gate
// G = c*U + s*V  ((c,s)=cos/sin(x0/2) even wires, (x1/2) odd wires).
// ---------------------------------------------------------------------------
__global__ void precompute_uv(const float* __restrict__ w, float* __restrict__ uv) {
    int t = threadIdx.x;
    if (t >= N_LAYERS * N_WIRES) return;
    int i = t & 7;
    float wx = w[t * 3 + 0], wy = w[t * 3 + 1], wz = w[t * 3 + 2];
    float sx, cx, sy, cy, sz, cz;
    sincosf(0.5f * wx, &sx, &cx);
    sincosf(0.5f * wy, &sy, &cy);
    sincosf(0.5f * wz, &sz, &cz);
    float A00r = cy * cx, A00i = sy * sx;
    float A01r = -sy * cx, A01i = -cy * sx;
    float A10r = sy * cx, A10i = -cy * sx;
    float A11r = cy * cx, A11i = -sy * sx;
    float U00r = A00r * cz + A00i * sz, U00i = A00i * cz - A00r * sz;
    float U01r = A01r * cz + A01i * sz, U01i = A01i * cz - A01r * sz;
    float U10r = A10r * cz - A10i * sz, U10i = A10i * cz + A10r * sz;
    float U11r = A11r * cz - A11i * sz, U11i = A11i * cz + A11r * sz;
    float V00r, V00i, V01r, V01i, V10r, V10i, V11r, V11i;
    if ((i & 1) == 0) {
        V00r = U01i; V00i = -U01r;
        V01r = U00i; V01i = -U00r;
        V10r = U11i; V10i = -U11r;
        V11r = U10i; V11i = -U10r;
    } else {
        V00r = U01r;  V00i = U01i;
        V01r = -U00r; V01i = -U00i;
        V10r = U11r;  V10i = U11i;
        V11r = -U10r; V11i = -U10i;
    }
    float* o = uv + t * 16;
    o[0] = U00r; o[1] = U00i; o[2] = U01r; o[3] = U01i;
    o[4] = U10r; o[5] = U10i; o[6] = U11r; o[7] = U11i;
    o[8] = V00r; o[9] = V00i; o[10] = V01r; o[11] = V01i;
    o[12] = V10r; o[13] = V10i; o[14] = V11r; o[15] = V11i;
}

// ---------------------------------------------------------------------------
// Grid circuit eval (round-1 kernel, validated): one wave per grid point
// g = a*49+b -> (x0,x1) = (2*pi*a/49, 2*pi*b/49). Writes E[i][g] (no pi).
// ---------------------------------------------------------------------------
__global__ __launch_bounds__(256) void qnn_grid_kernel(const float* __restrict__ uv,
                                                       float* __restrict__ E) {
    const int lane = threadIdx.x & 63;
    const int g = blockIdx.x * (blockDim.x >> 6) + (threadIdx.x >> 6);
    if (g >= NG2) return;

    const int ga = (g * 1338) >> 16;  // g/49, exact for g < 2404
    const int gb = g - ga * NG;
    const float step = (float)(2.0 * M_PI / 49.0);
    float x0 = step * (float)ga, x1 = step * (float)gb;
    float s0, c0, s1, c1;
    sincosf(0.5f * x0, &s0, &c0);
    sincosf(0.5f * x1, &s1, &c1);

    float ar[4] = {0.f, 0.f, 0.f, 0.f}, ai[4] = {0.f, 0.f, 0.f, 0.f};
    if (lane == 0) ar[0] = 1.0f;

    for (int l = 0; l < N_LAYERS; ++l) {
        const float* base = uv + l * 128;
        #pragma unroll
        for (int i = 0; i < 8; ++i) {
            const float* gm = base + i * 16;
            float ce = (i & 1) ? c1 : c0;
            float se = (i & 1) ? s1 : s0;
            float g00r = ce * gm[0] + se * gm[8],  g00i = ce * gm[1] + se * gm[9];
            float g01r = ce * gm[2] + se * gm[10], g01i = ce * gm[3] + se * gm[11];
            float g10r = ce * gm[4] + se * gm[12], g10i = ce * gm[5] + se * gm[13];
            float g11r = ce * gm[6] + se * gm[14], g11i = ce * gm[7] + se * gm[15];
            const int p = 7 - i;
            if (p >= 2) {
                const int m = 1 << (p - 2);
                const bool hi = (lane >> (p - 2)) & 1;
                float cor = hi ? g11r : g00r, coi = hi ? g11i : g00i;
                float cpr = hi ? g10r : g01r, cpi = hi ? g10i : g01i;
                #pragma unroll
                for (int j = 0; j < 4; ++j) {
                    float br = __shfl_xor(ar[j], m);
                    float bi = __shfl_xor(ai[j], m);
                    float nr = cor * ar[j] - coi * ai[j] + cpr * br - cpi * bi;
                    float ni = cor * ai[j] + coi * ar[j] + cpr * bi + cpi * br;
                    ar[j] = nr; ai[j] = ni;
                }
            } else {
                const int m = 1 << p;
                #pragma unroll
                for (int j0 = 0; j0 < 4; ++j0) {
                    if (j0 & m) continue;
                    const int j1 = j0 | m;
                    float a_r = ar[j0], a_i = ai[j0], b_r = ar[j1], b_i = ai[j1];
                    ar[j0] = g00r * a_r - g00i * a_i + g01r * b_r - g01i * b_i;
                    ai[j0] = g00r * a_i + g00i * a_r + g01r * b_i + g01i * b_r;
                    ar[j1] = g10r * a_r - g10i * a_i + g11r * b_r - g11i * b_i;
                    ai[j1] = g10r * a_i + g10i * a_r + g11r * b_i + g11i * b_r;
                }
            }
        }
        #pragma unroll
        for (int i = 0; i < 7; ++i) {
            const int pc = 7 - i, pt = 6 - i;
            if (pt >= 2) {
                const int m = 1 << (pt - 2);
                const bool ctrl = (lane >> (pc - 2)) & 1;
                #pragma unroll
                for (int j = 0; j < 4; ++j) {
                    float br = __shfl_xor(ar[j], m);
                    float bi = __shfl_xor(ai[j], m);
                    ar[j] = ctrl ? br : ar[j];
                    ai[j] = ctrl ? bi : ai[j];
                }
            } else if (pt == 1) {
                const bool ctrl = lane & 1;
                float n0r = ctrl ? ar[2] : ar[0], n0i = ctrl ? ai[2] : ai[0];
                float n2r = ctrl ? ar[0] : ar[2], n2i = ctrl ? ai[0] : ai[2];
                float n1r = ctrl ? ar[3] : ar[1], n1i = ctrl ? ai[3] : ai[1];
                float n3r = ctrl ? ar[1] : ar[3], n3i = ctrl ? ai[1] : ai[3];
                ar[0] = n0r; ai[0] = n0i; ar[1] = n1r; ai[1] = n1i;
                ar[2] = n2r; ai[2] = n2i; ar[3] = n3r; ai[3] = n3i;
            } else {
                float tr = ar[2], ti = ai[2];
                ar[2] = ar[3]; ai[2] = ai[3];
                ar[3] = tr;    ai[3] = ti;
            }
        }
    }

    float p0 = ar[0] * ar[0] + ai[0] * ai[0];
    float p1 = ar[1] * ar[1] + ai[1] * ai[1];
    float p2 = ar[2] * ar[2] + ai[2] * ai[2];
    float p3 = ar[3] * ar[3] + ai[3] * ai[3];
    float sAll = p0 + p1 + p2 + p3;

    float ev[8];
    #pragma unroll
    for (int i = 0; i < 6; ++i) ev[i] = ((lane >> (5 - i)) & 1) ? -sAll : sAll;
    ev[6] = p0 + p1 - p2 - p3;
    ev[7] = p0 - p1 + p2 - p3;

    #pragma unroll
    for (int i = 0; i < 8; ++i) {
        #pragma unroll
        for (int s = 1; s < 64; s <<= 1) ev[i] += __shfl_xor(ev[i], s);
    }

    if (lane == 0) {
        #pragma unroll
        for (int i = 0; i < 8; ++i) E[i * NG2 + g] = ev[i];
    }
}

// ---------------------------------------------------------------------------
// Stage 3a: G[i][a][k] = sum_b E[i][a*49+b] * T[b][k]
// T[b][0]=1/49, T[b][2n-1]=(2/49)cos(2*pi*n*b/49), T[b][2n]=(2/49)sin(...)
// block 64 threads = k; grid (49, 8) = (a, i).
// ---------------------------------------------------------------------------
__global__ void dft_b(const float* __restrict__ E, float* __restrict__ G) {
    const int a = blockIdx.x, i = blockIdx.y, k = threadIdx.x;
    if (k >= NG) return;
    const float* Er = E + i * NG2 + a * NG;
    float acc = 0.f;
    if (k == 0) {
        for (int b = 0; b < NG; ++b) acc += Er[b];
        acc *= (1.0f / 49.0f);
    } else {
        int n = (k + 1) >> 1;
        float cs, ss;
        sincosf((float)(2.0 * M_PI / 49.0) * (float)n, &ss, &cs);
        float cb = 1.f, sb = 0.f;
        const bool use_cos = (k & 1);
        for (int b = 0; b < NG; ++b) {
            acc = fmaf(Er[b], use_cos ? cb : sb, acc);
            float cn = cb * cs - sb * ss;
            float sn = sb * cs + cb * ss;
            cb = cn; sb = sn;
        }
        acc *= (2.0f / 49.0f);
    }
    G[(i * NG + a) * NG + k] = acc;
}

// ---------------------------------------------------------------------------
// Stage 3b: F[i][kp][l] = sum_a T[a][kp] * G[i][a][l]  (F rows padded to 52)
// block 64 threads = l; grid (49, 8) = (kp, i).
// ---------------------------------------------------------------------------
__global__ void dft_a(const float* __restrict__ G, float* __restrict__ F) {
    const int kp = blockIdx.x, i = blockIdx.y, l = threadIdx.x;
    if (l >= NG) return;
    float acc = 0.f;
    if (kp == 0) {
        for (int a = 0; a < NG; ++a) acc += G[(i * NG + a) * NG + l];
        acc *= (1.0f / 49.0f);
    } else {
        int n = (kp + 1) >> 1;
        float cs, ss;
        sincosf((float)(2.0 * M_PI / 49.0) * (float)n, &ss, &cs);
        float ca = 1.f, sa = 0.f;
        const bool use_cos = (kp & 1);
        for (int a = 0; a < NG; ++a) {
            acc = fmaf(G[(i * NG + a) * NG + l], use_cos ? ca : sa, acc);
            float cn = ca * cs - sa * ss;
            float sn = sa * cs + ca * ss;
            ca = cn; sa = sn;
        }
        acc *= (2.0f / 49.0f);
    }
    F[(i * NG + kp) * FPAD + l] = acc;
}

// ---------------------------------------------------------------------------
// Final: out[b][i] = pi * v0(x0)^T F_i v1(x1), 4 outputs per block.y.
// v = [1, cos x, sin x, ..., cos 24x, sin 24x]; v1 in registers (unrolled),
// v0 via rolled recurrence over n. F rows are wave-uniform -> scalar loads.
// ---------------------------------------------------------------------------
__device__ __forceinline__ float dot52(const float* __restrict__ r, const float (&v)[FPAD]) {
    float t0 = 0.f, t1 = 0.f, t2 = 0.f, t3 = 0.f;
    #pragma unroll
    for (int l = 0; l < FPAD; l += 4) {
        t0 = fmaf(r[l + 0], v[l + 0], t0);
        t1 = fmaf(r[l + 1], v[l + 1], t1);
        t2 = fmaf(r[l + 2], v[l + 2], t2);
        t3 = fmaf(r[l + 3], v[l + 3], t3);
    }
    return (t0 + t1) + (t2 + t3);
}

__global__ __launch_bounds__(256) void contract_kernel(const float* __restrict__ x,
                                                       const float* __restrict__ F,
                                                       float* __restrict__ out, int B) {
    const int b = blockIdx.x * 256 + threadIdx.x;
    const int i0 = blockIdx.y * 4;
    if (b >= B) return;

    float2 xv = ((const float2*)x)[b];
    float s0, c0, s1, c1;
    sincosf(xv.x, &s0, &c0);
    sincosf(xv.y, &s1, &c1);

    float v1[FPAD];
    v1[0] = 1.0f; v1[1] = c1; v1[2] = s1;
    #pragma unroll
    for (int n = 2; n <= 24; ++n) {
        v1[2 * n - 1] = v1[2 * n - 3] * c1 - v1[2 * n - 2] * s1;
        v1[2 * n]     = v1[2 * n - 2] * c1 + v1[2 * n - 3] * s1;
    }
    v1[49] = 0.f; v1[50] = 0.f; v1[51] = 0.f;

    const float* base = F + (size_t)i0 * NG * FPAD;
    float acc[4];
    #pragma unroll
    for (int i = 0; i < 4; ++i) acc[i] = dot52(base + i * NG * FPAD, v1);  // k=0 row

    float Ck = c0, Sk = s0;
    #pragma unroll 1
    for (int n = 1; n <= 24; ++n) {
        const float* rn = base + (2 * n - 1) * FPAD;
        #pragma unroll
        for (int i = 0; i < 4; ++i) {
            float tC = dot52(rn + i * NG * FPAD, v1);
            float tS = dot52(rn + i * NG * FPAD + FPAD, v1);
            acc[i] = fmaf(Ck, tC, acc[i]);
            acc[i] = fmaf(Sk, tS, acc[i]);
        }
        float Cn = Ck * c0 - Sk * s0;
        float Sn = Sk * c0 + Ck * s0;
        Ck = Cn; Sk = Sn;
    }

    const float PI = 3.14159265358979323846f;
    float4 o = make_float4(PI * acc[0], PI * acc[1], PI * acc[2], PI * acc[3]);
    *((float4*)(out + (size_t)b * 8 + i0)) = o;
}

extern "C" void kernel_launch(void* const* d_in, const int* in_sizes, int n_in,
                              void* d_out, int out_size, void* d_ws, size_t ws_size,
                              hipStream_t stream) {
    (void)n_in; (void)out_size; (void)ws_size;
    const float* x = (const float*)d_in[0];
    const float* w = (const float*)d_in[1];
    float* out = (float*)d_out;
    char* ws = (char*)d_ws;
    float* uv = (float*)(ws);
    float* E  = (float*)(ws + WS_E_OFF);
    float* G  = (float*)(ws + WS_G_OFF);
    float* F  = (float*)(ws + WS_F_OFF);
    const int B = in_sizes[0] / 2;

    hipLaunchKernelGGL(precompute_uv, dim3(1), dim3(64), 0, stream, w, uv);

    // grid circuit eval: one wave per grid point, 4 waves/block
    hipLaunchKernelGGL(qnn_grid_kernel, dim3((NG2 + 3) / 4), dim3(256), 0, stream, uv, E);

    hipLaunchKernelGGL(dft_b, dim3(NG, 8), dim3(64), 0, stream, E, G);
    hipLaunchKernelGGL(dft_a, dim3(NG, 8), dim3(64), 0, stream, G, F);

    hipLaunchKernelGGL(contract_kernel, dim3((B + 255) / 256, 2), dim3(256), 0, stream,
                       x, F, out, B);
}